// Round 11
// baseline (1448.535 us; speedup 1.0000x reference)
//
#include <hip/hip_runtime.h>
#include <hip/hip_bf16.h>
#include <hip/hip_fp16.h>

#define LEAKY_SLOPE 0.2f

__device__ __forceinline__ float leaky(float x) { return x > 0.f ? x : LEAKY_SLOPE * x; }

// monotone float<->uint key map (order-preserving for atomicMax/Min on unsigned)
__device__ __forceinline__ unsigned fkey(float f)
{
    unsigned u = __float_as_uint(f);
    return (u & 0x80000000u) ? ~u : (u | 0x80000000u);
}
__device__ __forceinline__ float key_to_float(unsigned k)
{
    unsigned u = (k & 0x80000000u) ? (k & 0x7fffffffu) : ~k;
    return __uint_as_float(u);
}

// bf16-pair unpack: low16 -> head0, high16 -> head1
__device__ __forceinline__ float bl(unsigned u) { return __uint_as_float(u << 16); }
__device__ __forceinline__ float bh(unsigned u) { return __uint_as_float(u & 0xffff0000u); }

// round-to-nearest-even bf16 packing: lo -> low 16 bits, hi -> high 16 bits
__device__ __forceinline__ unsigned pack_bf16_pair(float lo, float hi)
{
    unsigned blv = __float_as_uint(lo);
    blv = (blv + 0x7fffu + ((blv >> 16) & 1u)) >> 16;
    unsigned bhv = __float_as_uint(hi);
    bhv = (bhv + 0x7fffu + ((bhv >> 16) & 1u)) & 0xffff0000u;
    return blv | bhv;
}

// ---------------------------------------------------------------------------
// GEMM: h1 = x @ W1, h1 stored bf16-packed {head0,head1} per channel.
// Epilogue: per-node alpha_src/alpha_dst + global max of alpha_src per head
// (block-local max -> 2 atomics/block on keys[0..1]).
// ---------------------------------------------------------------------------
__global__ __launch_bounds__(256) void gemm1_kernel(
    const float* __restrict__ x, const float* __restrict__ W1,
    const float* __restrict__ a_s, const float* __restrict__ a_d,
    unsigned* __restrict__ h1b, float2* __restrict__ as1, float2* __restrict__ ad1,
    unsigned* __restrict__ keys, int n)
{
    __shared__ float wlds[128 * 128];   // 64 KB, swizzled columns
    __shared__ float smax0[8], smax1[8];
    int tid = threadIdx.x;
    // stage W1 swizzled: col j -> p = (j&63)*2 + (j>>6)  (p = channel*2 + head)
    for (int i = tid; i < 128 * 128; i += 256) {
        int k = i >> 7, j = i & 127;
        wlds[(k << 7) + ((j & 63) * 2 + (j >> 6))] = W1[i];
    }
    int l  = tid & 31;   // lane within 32-group
    int g  = tid >> 5;   // group 0..7 -> node offset within block-iter
    int p0 = l * 4;      // swizzled column base for this thread
    float aS[4], aD[4];
#pragma unroll
    for (int i = 0; i < 4; ++i) {
        int p = p0 + i;
        int j = ((p & 1) << 6) + (p >> 1);   // unswizzle
        aS[i] = a_s[j];
        aD[i] = a_d[j];
    }
    __syncthreads();
    int lane = tid & 63;
    float rmax0 = -INFINITY, rmax1 = -INFINITY;

    for (int base = blockIdx.x * 8; base < n; base += gridDim.x * 8) {
        int node = base + g;
        bool valid = node < n;
        float4 xr = make_float4(0.f, 0.f, 0.f, 0.f);
        if (valid) xr = *(const float4*)(x + (size_t)node * 128 + l * 4);
        float acc0 = 0.f, acc1 = 0.f, acc2 = 0.f, acc3 = 0.f;
#pragma unroll 8
        for (int k4 = 0; k4 < 32; ++k4) {
            int srcl = k4 + (lane & 32);
            float x0 = __shfl(xr.x, srcl);
            float x1 = __shfl(xr.y, srcl);
            float x2 = __shfl(xr.z, srcl);
            float x3 = __shfl(xr.w, srcl);
            const float4 w0 = *(const float4*)&wlds[(k4 * 4 + 0) * 128 + p0];
            const float4 w1 = *(const float4*)&wlds[(k4 * 4 + 1) * 128 + p0];
            const float4 w2 = *(const float4*)&wlds[(k4 * 4 + 2) * 128 + p0];
            const float4 w3 = *(const float4*)&wlds[(k4 * 4 + 3) * 128 + p0];
            acc0 = fmaf(x0, w0.x, acc0); acc1 = fmaf(x0, w0.y, acc1);
            acc2 = fmaf(x0, w0.z, acc2); acc3 = fmaf(x0, w0.w, acc3);
            acc0 = fmaf(x1, w1.x, acc0); acc1 = fmaf(x1, w1.y, acc1);
            acc2 = fmaf(x1, w1.z, acc2); acc3 = fmaf(x1, w1.w, acc3);
            acc0 = fmaf(x2, w2.x, acc0); acc1 = fmaf(x2, w2.y, acc1);
            acc2 = fmaf(x2, w2.z, acc2); acc3 = fmaf(x2, w2.w, acc3);
            acc0 = fmaf(x3, w3.x, acc0); acc1 = fmaf(x3, w3.y, acc1);
            acc2 = fmaf(x3, w3.z, acc2); acc3 = fmaf(x3, w3.w, acc3);
        }
        if (valid) {
            unsigned u0 = pack_bf16_pair(acc0, acc1);
            unsigned u1 = pack_bf16_pair(acc2, acc3);
            *(uint2*)&h1b[(size_t)node * 64 + 2 * l] = make_uint2(u0, u1);
            float vs0 = acc0 * aS[0] + acc2 * aS[2];   // head0
            float vs1 = acc1 * aS[1] + acc3 * aS[3];   // head1
            float vd0 = acc0 * aD[0] + acc2 * aD[2];
            float vd1 = acc1 * aD[1] + acc3 * aD[3];
#pragma unroll
            for (int off = 1; off < 32; off <<= 1) {
                vs0 += __shfl_xor(vs0, off);
                vs1 += __shfl_xor(vs1, off);
                vd0 += __shfl_xor(vd0, off);
                vd1 += __shfl_xor(vd1, off);
            }
            if (l == 0) {
                as1[node] = make_float2(vs0, vs1);
                ad1[node] = make_float2(vd0, vd1);
                rmax0 = fmaxf(rmax0, vs0);
                rmax1 = fmaxf(rmax1, vs1);
            }
        }
    }
    if (l == 0) { smax0[g] = rmax0; smax1[g] = rmax1; }
    __syncthreads();
    if (tid == 0) {
        float m0 = smax0[0], m1 = smax1[0];
#pragma unroll
        for (int i = 1; i < 8; ++i) { m0 = fmaxf(m0, smax0[i]); m1 = fmaxf(m1, smax1[i]); }
        atomicMax(&keys[0], fkey(m0));
        atomicMax(&keys[1], fkey(m1));
    }
}

// ---------------------------------------------------------------------------
// CSR build via two-level counting sort (no global atomics, L2-local writes).
// ---------------------------------------------------------------------------
#define CHUNK 8192

__global__ __launch_bounds__(256) void chist_kernel(
    const int* __restrict__ dst, int E, int NB, int NC, int* __restrict__ osc)
{
    __shared__ int h[256];
    int tid = threadIdx.x, c = blockIdx.x;
    h[tid] = 0;
    __syncthreads();
    int e0 = c * CHUNK, e1 = min(e0 + CHUNK, E);
    for (int e = e0 + tid; e < e1; e += 256)
        atomicAdd(&h[dst[e] >> 8], 1);
    __syncthreads();
    if (tid < NB) osc[tid * NC + c] = h[tid];
}

__global__ __launch_bounds__(1024) void oscan_kernel(int* __restrict__ osc, int len)
{
    __shared__ int wsum[16];
    int tid = threadIdx.x;
    int seg = (len + 1023) / 1024;
    int st = tid * seg, en = min(st + seg, len);
    int s = 0;
    for (int i = st; i < en; ++i) s += osc[i];
    int lane = tid & 63, w = tid >> 6;
    int incl = s;
#pragma unroll
    for (int off = 1; off < 64; off <<= 1) {
        int t = __shfl_up(incl, off);
        if (lane >= off) incl += t;
    }
    if (lane == 63) wsum[w] = incl;
    __syncthreads();
    int wb = 0;
    for (int i = 0; i < w; ++i) wb += wsum[i];
    int run = wb + incl - s;
    for (int i = st; i < en; ++i) { int v = osc[i]; osc[i] = run; run += v; }
}

__global__ __launch_bounds__(256) void cscatter_kernel(
    const int* __restrict__ src, const int* __restrict__ dst,
    int E, int NB, int NC, const int* __restrict__ osc, int2* __restrict__ pairs)
{
    __shared__ int cur[256];
    int tid = threadIdx.x, c = blockIdx.x;
    if (tid < NB) cur[tid] = osc[tid * NC + c];
    __syncthreads();
    int e0 = c * CHUNK, e1 = min(e0 + CHUNK, E);
    for (int e = e0 + tid; e < e1; e += 256) {
        int d = dst[e];
        int p = atomicAdd(&cur[d >> 8], 1);
        pairs[p] = make_int2(src[e], d);
    }
}

__global__ __launch_bounds__(256) void fsort_kernel(
    const int2* __restrict__ pairs, const int* __restrict__ osc,
    int E, int n, int NB, int NC,
    int* __restrict__ row_start, int* __restrict__ csr_src)
{
    __shared__ int fh[256];
    __shared__ int cur[256];
    __shared__ int wsum[4];
    int tid = threadIdx.x, b = blockIdx.x;
    int rbase = osc[b * NC];
    int rend  = (b + 1 < NB) ? osc[(b + 1) * NC] : E;
    fh[tid] = 0;
    __syncthreads();
    for (int i = rbase + tid; i < rend; i += 256)
        atomicAdd(&fh[pairs[i].y & 255], 1);
    __syncthreads();
    int v = fh[tid];
    int lane = tid & 63, w = tid >> 6;
    int incl = v;
#pragma unroll
    for (int off = 1; off < 64; off <<= 1) {
        int t = __shfl_up(incl, off);
        if (lane >= off) incl += t;
    }
    if (lane == 63) wsum[w] = incl;
    __syncthreads();
    int wb = 0;
    for (int i = 0; i < w; ++i) wb += wsum[i];
    int excl = wb + incl - v;
    int node = b * 256 + tid;
    if (node < n) row_start[node] = rbase + excl;
    cur[tid] = rbase + excl;
    __syncthreads();
    for (int i = rbase + tid; i < rend; i += 256) {
        int2 pr = pairs[i];
        int p = atomicAdd(&cur[pr.y & 255], 1);
        csr_src[p] = pr.x;
    }
    if (b == 0 && tid == 0) row_start[n] = E;
}

// ---------------------------------------------------------------------------
// Layer-1 gather v3: one wave per node. Softmax uses precomputed upper bound
// m = leaky(gmax_alpha_src + ad) -> no online max, no per-chunk reductions.
// Lanes = 4 edge-groups x 16 channels-quads; uint4 row loads; f16-packed
// weight broadcast. Epilogue: bias+relu, h2 = h.W2 wave-dot, h2 range atomics.
// ---------------------------------------------------------------------------
__global__ __launch_bounds__(256) void gather1_kernel(
    const unsigned* __restrict__ h1b, const float2* __restrict__ as1, const float2* __restrict__ ad1,
    const int* __restrict__ row_start, const int* __restrict__ csr_src,
    const float* __restrict__ b1, const float* __restrict__ W2,
    unsigned* __restrict__ keys, float* __restrict__ h2, int n)
{
    int wid = threadIdx.x >> 6, lane = threadIdx.x & 63;
    int v = blockIdx.x * 4 + wid;
    if (v >= n) return;
    int grp = lane >> 4, li = lane & 15;

    float gm0 = key_to_float(keys[0]);
    float gm1 = key_to_float(keys[1]);

    float2 ad = ad1[v];
    float2 asv = as1[v];
    float m0 = leaky(gm0 + ad.x), m1 = leaky(gm1 + ad.y);
    float ps0 = __expf(leaky(asv.x + ad.x) - m0);   // self-loop weight
    float ps1 = __expf(leaky(asv.y + ad.y) - m1);

    float a0x = 0.f, a0y = 0.f, a0z = 0.f, a0w = 0.f;   // head0, channels 4li+0..3
    float a1x = 0.f, a1y = 0.f, a1z = 0.f, a1w = 0.f;   // head1
    if (grp == 0) {
        uint4 hu = *(const uint4*)&h1b[(size_t)v * 64 + li * 4];
        a0x = ps0 * bl(hu.x); a1x = ps1 * bh(hu.x);
        a0y = ps0 * bl(hu.y); a1y = ps1 * bh(hu.y);
        a0z = ps0 * bl(hu.z); a1z = ps1 * bh(hu.z);
        a0w = ps0 * bl(hu.w); a1w = ps1 * bh(hu.w);
    }
    float s0l = 0.f, s1l = 0.f;

    int t0 = row_start[v], t1 = row_start[v + 1];
    for (int t = t0; t < t1; t += 64) {
        int nv = t1 - t; if (nv > 64) nv = 64;
        int srcn = v;
        float p0 = 0.f, p1 = 0.f;
        if (lane < nv) {
            srcn = csr_src[t + lane];
            float2 as = as1[srcn];
            p0 = __expf(leaky(as.x + ad.x) - m0);
            p1 = __expf(leaky(as.y + ad.y) - m1);
        }
        s0l += p0; s1l += p1;
        int pk = (int)__builtin_bit_cast(unsigned, __floats2half2_rn(p0, p1));
        int jmax = (nv + 3) >> 2;
        for (int j = 0; j < jmax; ++j) {
            int idx = 4 * j + grp;
            int sj = __shfl(srcn, idx);
            __half2 hp = __builtin_bit_cast(__half2, (unsigned)__shfl(pk, idx));
            float w0 = __half2float(__low2half(hp));
            float w1 = __half2float(__high2half(hp));
            uint4 hu = *(const uint4*)&h1b[(size_t)sj * 64 + li * 4];
            a0x = fmaf(w0, bl(hu.x), a0x); a1x = fmaf(w1, bh(hu.x), a1x);
            a0y = fmaf(w0, bl(hu.y), a0y); a1y = fmaf(w1, bh(hu.y), a1y);
            a0z = fmaf(w0, bl(hu.z), a0z); a1z = fmaf(w1, bh(hu.z), a1z);
            a0w = fmaf(w0, bl(hu.w), a0w); a1w = fmaf(w1, bh(hu.w), a1w);
        }
    }
    // sum s over all 64 lanes (masked lanes contributed 0)
#pragma unroll
    for (int off = 32; off >= 1; off >>= 1) {
        s0l += __shfl_xor(s0l, off);
        s1l += __shfl_xor(s1l, off);
    }
    float inv0 = 1.f / (s0l + ps0 + 1e-16f);
    float inv1 = 1.f / (s1l + ps1 + 1e-16f);
    // sum accumulators across the 4 edge-groups (lanes stride 16)
#pragma unroll
    for (int off = 16; off <= 32; off <<= 1) {
        a0x += __shfl_xor(a0x, off); a1x += __shfl_xor(a1x, off);
        a0y += __shfl_xor(a0y, off); a1y += __shfl_xor(a1y, off);
        a0z += __shfl_xor(a0z, off); a1z += __shfl_xor(a1z, off);
        a0w += __shfl_xor(a0w, off); a1w += __shfl_xor(a1w, off);
    }
    const float4 b0v = *(const float4*)&b1[4 * li];
    const float4 b1v = *(const float4*)&b1[64 + 4 * li];
    const float4 w0v = *(const float4*)&W2[4 * li];
    const float4 w1v = *(const float4*)&W2[64 + 4 * li];
    float o;
    float hv = 0.f;
    o = fmaxf(fmaf(a0x, inv0, b0v.x), 0.f); hv = fmaf(o, w0v.x, hv);
    o = fmaxf(fmaf(a0y, inv0, b0v.y), 0.f); hv = fmaf(o, w0v.y, hv);
    o = fmaxf(fmaf(a0z, inv0, b0v.z), 0.f); hv = fmaf(o, w0v.z, hv);
    o = fmaxf(fmaf(a0w, inv0, b0v.w), 0.f); hv = fmaf(o, w0v.w, hv);
    o = fmaxf(fmaf(a1x, inv1, b1v.x), 0.f); hv = fmaf(o, w1v.x, hv);
    o = fmaxf(fmaf(a1y, inv1, b1v.y), 0.f); hv = fmaf(o, w1v.y, hv);
    o = fmaxf(fmaf(a1z, inv1, b1v.z), 0.f); hv = fmaf(o, w1v.z, hv);
    o = fmaxf(fmaf(a1w, inv1, b1v.w), 0.f); hv = fmaf(o, w1v.w, hv);
#pragma unroll
    for (int off = 1; off <= 8; off <<= 1) hv += __shfl_xor(hv, off);
    if (lane == 0) {
        h2[v] = hv;
        atomicMax(&keys[2], fkey(hv));
        atomicMin(&keys[3], fkey(hv));
    }
}

// ---------------------------------------------------------------------------
// Layer-2 gather: branchless via precomputed bound m = leaky(B + ad), where
// B = max over all possible src of as2*h (from h2 global min/max keys).
// ---------------------------------------------------------------------------
__global__ void gather2_kernel(
    const float* __restrict__ h2, const int* __restrict__ row_start, const int* __restrict__ csr_src,
    const float* __restrict__ aS2, const float* __restrict__ aD2, const float* __restrict__ b2,
    const unsigned* __restrict__ keys, float* __restrict__ out, int n)
{
    int v = blockIdx.x * 256 + threadIdx.x;
    if (v >= n) return;
    float as2 = aS2[0], ad2c = aD2[0];
    float hmax = key_to_float(keys[2]);
    float hmin = key_to_float(keys[3]);
    float B = as2 >= 0.f ? as2 * hmax : as2 * hmin;
    float hv = h2[v];
    float ad = hv * ad2c;
    float m = leaky(B + ad);
    float ps = __expf(leaky(fmaf(hv, as2, ad)) - m);
    float s = ps, num = ps * hv;
    int t1 = row_start[v + 1];
    for (int t = row_start[v]; t < t1; ++t) {
        float hs = h2[csr_src[t]];
        float p = __expf(leaky(fmaf(hs, as2, ad)) - m);
        s += p;
        num = fmaf(p, hs, num);
    }
    float o = num / (s + 1e-16f) + b2[0];
    out[v] = 1.f / (1.f + __expf(-o));
}

// ---------------------------------------------------------------------------
extern "C" void kernel_launch(void* const* d_in, const int* in_sizes, int n_in,
                              void* d_out, int out_size, void* d_ws, size_t ws_size,
                              hipStream_t stream)
{
    const float* x      = (const float*)d_in[0];
    const int*   eidx   = (const int*)  d_in[1];
    const float* W1     = (const float*)d_in[2];
    const float* a_src1 = (const float*)d_in[3];
    const float* a_dst1 = (const float*)d_in[4];
    const float* b1     = (const float*)d_in[5];
    const float* W2     = (const float*)d_in[6];
    const float* a_src2 = (const float*)d_in[7];
    const float* a_dst2 = (const float*)d_in[8];
    const float* b2     = (const float*)d_in[9];

    int n = in_sizes[0] / 128;
    int E = in_sizes[1] / 2;
    const int* src = eidx;
    const int* dst = eidx + E;

    int NC = (E + CHUNK - 1) / CHUNK;   // 196 for E=1.6M
    int NB = (n + 255) / 256;           // 196 for n=50000 (<=256 required)

    char* ws = (char*)d_ws;
    size_t off = 0;
    auto alloc = [&](size_t bytes) { size_t o = off; off += (bytes + 255) & ~(size_t)255; return o; };

    unsigned* h1b   = (unsigned*)(ws + alloc((size_t)n * 64 * 4));   // 12.8 MB
    float2* as1     = (float2*)(ws + alloc((size_t)n * 8));
    float2* ad1     = (float2*)(ws + alloc((size_t)n * 8));
    float*  h2      = (float*) (ws + alloc((size_t)n * 4));
    int*    rowst   = (int*)   (ws + alloc((size_t)(n + 1) * 4));
    unsigned* keys  = (unsigned*)(ws + alloc(4 * 4));                // [as0max, as1max, h2max, h2min]
    int*    osc     = (int*)   (ws + alloc((size_t)NB * NC * 4));    // 153 KB
    int2*   pairs   = (int2*)  (ws + alloc((size_t)E * 8));          // 12.8 MB
    int*    csr_src = (int*)   (ws + alloc((size_t)E * 4));          // 6.4 MB
    (void)ws_size; (void)n_in; (void)out_size;

    hipMemsetAsync(keys, 0x00, 12, stream);        // max slots -> smallest key
    hipMemsetAsync(keys + 3, 0xFF, 4, stream);     // min slot  -> largest key

    gemm1_kernel<<<1024, 256, 0, stream>>>(x, W1, a_src1, a_dst1, h1b, as1, ad1, keys, n);

    chist_kernel<<<NC, 256, 0, stream>>>(dst, E, NB, NC, osc);
    oscan_kernel<<<1, 1024, 0, stream>>>(osc, NB * NC);
    cscatter_kernel<<<NC, 256, 0, stream>>>(src, dst, E, NB, NC, osc, pairs);
    fsort_kernel<<<NB, 256, 0, stream>>>(pairs, osc, E, n, NB, NC, rowst, csr_src);

    gather1_kernel<<<(n + 3) / 4, 256, 0, stream>>>(h1b, as1, ad1, rowst, csr_src, b1, W2,
                                                    keys, h2, n);
    gather2_kernel<<<(n + 255) / 256, 256, 0, stream>>>(h2, rowst, csr_src, a_src2, a_dst2, b2,
                                                        keys, (float*)d_out, n);
}

// Round 13
// 346.578 us; speedup vs baseline: 4.1795x; 4.1795x over previous
//
#include <hip/hip_runtime.h>
#include <hip/hip_bf16.h>
#include <hip/hip_fp16.h>

#define LEAKY_SLOPE 0.2f

__device__ __forceinline__ float leaky(float x) { return x > 0.f ? x : LEAKY_SLOPE * x; }

// monotone float<->uint key map (order-preserving for atomicMax/Min on unsigned)
__device__ __forceinline__ unsigned fkey(float f)
{
    unsigned u = __float_as_uint(f);
    return (u & 0x80000000u) ? ~u : (u | 0x80000000u);
}
__device__ __forceinline__ float key_to_float(unsigned k)
{
    unsigned u = (k & 0x80000000u) ? (k & 0x7fffffffu) : ~k;
    return __uint_as_float(u);
}

// bf16-pair unpack: low16 -> head0, high16 -> head1
__device__ __forceinline__ float bl(unsigned u) { return __uint_as_float(u << 16); }
__device__ __forceinline__ float bh(unsigned u) { return __uint_as_float(u & 0xffff0000u); }

// round-to-nearest-even bf16 packing: lo -> low 16 bits, hi -> high 16 bits
__device__ __forceinline__ unsigned pack_bf16_pair(float lo, float hi)
{
    unsigned blv = __float_as_uint(lo);
    blv = (blv + 0x7fffu + ((blv >> 16) & 1u)) >> 16;
    unsigned bhv = __float_as_uint(hi);
    bhv = (bhv + 0x7fffu + ((bhv >> 16) & 1u)) & 0xffff0000u;
    return blv | bhv;
}

// ---------------------------------------------------------------------------
// GEMM: h1 = x @ W1, h1 stored bf16-packed {head0,head1} per channel.
// Epilogue: per-node alpha_src/alpha_dst + global max of alpha_src per head
// (block-local max -> 2 atomics/block on keys[0..1]; keys is read-only for
// all later kernels -> no contention).
// ---------------------------------------------------------------------------
__global__ __launch_bounds__(256) void gemm1_kernel(
    const float* __restrict__ x, const float* __restrict__ W1,
    const float* __restrict__ a_s, const float* __restrict__ a_d,
    unsigned* __restrict__ h1b, float2* __restrict__ as1, float2* __restrict__ ad1,
    unsigned* __restrict__ keys, int n)
{
    __shared__ float wlds[128 * 128];   // 64 KB, swizzled columns
    __shared__ float smax0[8], smax1[8];
    int tid = threadIdx.x;
    // stage W1 swizzled: col j -> p = (j&63)*2 + (j>>6)  (p = channel*2 + head)
    for (int i = tid; i < 128 * 128; i += 256) {
        int k = i >> 7, j = i & 127;
        wlds[(k << 7) + ((j & 63) * 2 + (j >> 6))] = W1[i];
    }
    int l  = tid & 31;   // lane within 32-group
    int g  = tid >> 5;   // group 0..7 -> node offset within block-iter
    int p0 = l * 4;      // swizzled column base for this thread
    float aS[4], aD[4];
#pragma unroll
    for (int i = 0; i < 4; ++i) {
        int p = p0 + i;
        int j = ((p & 1) << 6) + (p >> 1);   // unswizzle
        aS[i] = a_s[j];
        aD[i] = a_d[j];
    }
    __syncthreads();
    int lane = tid & 63;
    float rmax0 = -INFINITY, rmax1 = -INFINITY;

    for (int base = blockIdx.x * 8; base < n; base += gridDim.x * 8) {
        int node = base + g;
        bool valid = node < n;
        float4 xr = make_float4(0.f, 0.f, 0.f, 0.f);
        if (valid) xr = *(const float4*)(x + (size_t)node * 128 + l * 4);
        float acc0 = 0.f, acc1 = 0.f, acc2 = 0.f, acc3 = 0.f;
#pragma unroll 8
        for (int k4 = 0; k4 < 32; ++k4) {
            int srcl = k4 + (lane & 32);
            float x0 = __shfl(xr.x, srcl);
            float x1 = __shfl(xr.y, srcl);
            float x2 = __shfl(xr.z, srcl);
            float x3 = __shfl(xr.w, srcl);
            const float4 w0 = *(const float4*)&wlds[(k4 * 4 + 0) * 128 + p0];
            const float4 w1 = *(const float4*)&wlds[(k4 * 4 + 1) * 128 + p0];
            const float4 w2 = *(const float4*)&wlds[(k4 * 4 + 2) * 128 + p0];
            const float4 w3 = *(const float4*)&wlds[(k4 * 4 + 3) * 128 + p0];
            acc0 = fmaf(x0, w0.x, acc0); acc1 = fmaf(x0, w0.y, acc1);
            acc2 = fmaf(x0, w0.z, acc2); acc3 = fmaf(x0, w0.w, acc3);
            acc0 = fmaf(x1, w1.x, acc0); acc1 = fmaf(x1, w1.y, acc1);
            acc2 = fmaf(x1, w1.z, acc2); acc3 = fmaf(x1, w1.w, acc3);
            acc0 = fmaf(x2, w2.x, acc0); acc1 = fmaf(x2, w2.y, acc1);
            acc2 = fmaf(x2, w2.z, acc2); acc3 = fmaf(x2, w2.w, acc3);
            acc0 = fmaf(x3, w3.x, acc0); acc1 = fmaf(x3, w3.y, acc1);
            acc2 = fmaf(x3, w3.z, acc2); acc3 = fmaf(x3, w3.w, acc3);
        }
        if (valid) {
            unsigned u0 = pack_bf16_pair(acc0, acc1);
            unsigned u1 = pack_bf16_pair(acc2, acc3);
            *(uint2*)&h1b[(size_t)node * 64 + 2 * l] = make_uint2(u0, u1);
            float vs0 = acc0 * aS[0] + acc2 * aS[2];   // head0
            float vs1 = acc1 * aS[1] + acc3 * aS[3];   // head1
            float vd0 = acc0 * aD[0] + acc2 * aD[2];
            float vd1 = acc1 * aD[1] + acc3 * aD[3];
#pragma unroll
            for (int off = 1; off < 32; off <<= 1) {
                vs0 += __shfl_xor(vs0, off);
                vs1 += __shfl_xor(vs1, off);
                vd0 += __shfl_xor(vd0, off);
                vd1 += __shfl_xor(vd1, off);
            }
            if (l == 0) {
                as1[node] = make_float2(vs0, vs1);
                ad1[node] = make_float2(vd0, vd1);
                rmax0 = fmaxf(rmax0, vs0);
                rmax1 = fmaxf(rmax1, vs1);
            }
        }
    }
    if (l == 0) { smax0[g] = rmax0; smax1[g] = rmax1; }
    __syncthreads();
    if (tid == 0) {
        float m0 = smax0[0], m1 = smax1[0];
#pragma unroll
        for (int i = 1; i < 8; ++i) { m0 = fmaxf(m0, smax0[i]); m1 = fmaxf(m1, smax1[i]); }
        atomicMax(&keys[0], fkey(m0));
        atomicMax(&keys[1], fkey(m1));
    }
}

// ---------------------------------------------------------------------------
// CSR build via two-level counting sort (no global atomics, L2-local writes).
// ---------------------------------------------------------------------------
#define CHUNK 8192

__global__ __launch_bounds__(256) void chist_kernel(
    const int* __restrict__ dst, int E, int NB, int NC, int* __restrict__ osc)
{
    __shared__ int h[256];
    int tid = threadIdx.x, c = blockIdx.x;
    h[tid] = 0;
    __syncthreads();
    int e0 = c * CHUNK, e1 = min(e0 + CHUNK, E);
    for (int e = e0 + tid; e < e1; e += 256)
        atomicAdd(&h[dst[e] >> 8], 1);
    __syncthreads();
    if (tid < NB) osc[tid * NC + c] = h[tid];
}

__global__ __launch_bounds__(1024) void oscan_kernel(int* __restrict__ osc, int len)
{
    __shared__ int wsum[16];
    int tid = threadIdx.x;
    int seg = (len + 1023) / 1024;
    int st = tid * seg, en = min(st + seg, len);
    int s = 0;
    for (int i = st; i < en; ++i) s += osc[i];
    int lane = tid & 63, w = tid >> 6;
    int incl = s;
#pragma unroll
    for (int off = 1; off < 64; off <<= 1) {
        int t = __shfl_up(incl, off);
        if (lane >= off) incl += t;
    }
    if (lane == 63) wsum[w] = incl;
    __syncthreads();
    int wb = 0;
    for (int i = 0; i < w; ++i) wb += wsum[i];
    int run = wb + incl - s;
    for (int i = st; i < en; ++i) { int v = osc[i]; osc[i] = run; run += v; }
}

__global__ __launch_bounds__(256) void cscatter_kernel(
    const int* __restrict__ src, const int* __restrict__ dst,
    int E, int NB, int NC, const int* __restrict__ osc, int2* __restrict__ pairs)
{
    __shared__ int cur[256];
    int tid = threadIdx.x, c = blockIdx.x;
    if (tid < NB) cur[tid] = osc[tid * NC + c];
    __syncthreads();
    int e0 = c * CHUNK, e1 = min(e0 + CHUNK, E);
    for (int e = e0 + tid; e < e1; e += 256) {
        int d = dst[e];
        int p = atomicAdd(&cur[d >> 8], 1);
        pairs[p] = make_int2(src[e], d);
    }
}

__global__ __launch_bounds__(256) void fsort_kernel(
    const int2* __restrict__ pairs, const int* __restrict__ osc,
    int E, int n, int NB, int NC,
    int* __restrict__ row_start, int* __restrict__ csr_src)
{
    __shared__ int fh[256];
    __shared__ int cur[256];
    __shared__ int wsum[4];
    int tid = threadIdx.x, b = blockIdx.x;
    int rbase = osc[b * NC];
    int rend  = (b + 1 < NB) ? osc[(b + 1) * NC] : E;
    fh[tid] = 0;
    __syncthreads();
    for (int i = rbase + tid; i < rend; i += 256)
        atomicAdd(&fh[pairs[i].y & 255], 1);
    __syncthreads();
    int v = fh[tid];
    int lane = tid & 63, w = tid >> 6;
    int incl = v;
#pragma unroll
    for (int off = 1; off < 64; off <<= 1) {
        int t = __shfl_up(incl, off);
        if (lane >= off) incl += t;
    }
    if (lane == 63) wsum[w] = incl;
    __syncthreads();
    int wb = 0;
    for (int i = 0; i < w; ++i) wb += wsum[i];
    int excl = wb + incl - v;
    int node = b * 256 + tid;
    if (node < n) row_start[node] = rbase + excl;
    cur[tid] = rbase + excl;
    __syncthreads();
    for (int i = rbase + tid; i < rend; i += 256) {
        int2 pr = pairs[i];
        int p = atomicAdd(&cur[pr.y & 255], 1);
        csr_src[p] = pr.x;
    }
    if (b == 0 && tid == 0) row_start[n] = E;
}

// ---------------------------------------------------------------------------
// Layer-1 gather v4: bound-softmax (keys[0..1] read-only here) + 4-group
// gather loop. NO atomics in this kernel -> no contended cache line.
// ---------------------------------------------------------------------------
__global__ __launch_bounds__(256) void gather1_kernel(
    const unsigned* __restrict__ h1b, const float2* __restrict__ as1, const float2* __restrict__ ad1,
    const int* __restrict__ row_start, const int* __restrict__ csr_src,
    const float* __restrict__ b1, const float* __restrict__ W2,
    const unsigned* __restrict__ keys, float* __restrict__ h2, int n)
{
    int wid = threadIdx.x >> 6, lane = threadIdx.x & 63;
    int v = blockIdx.x * 4 + wid;
    if (v >= n) return;
    int grp = lane >> 4, li = lane & 15;

    float gm0 = key_to_float(keys[0]);
    float gm1 = key_to_float(keys[1]);

    float2 ad = ad1[v];
    float2 asv = as1[v];
    float m0 = leaky(gm0 + ad.x), m1 = leaky(gm1 + ad.y);
    float ps0 = __expf(leaky(asv.x + ad.x) - m0);   // self-loop weight
    float ps1 = __expf(leaky(asv.y + ad.y) - m1);

    float a0x = 0.f, a0y = 0.f, a0z = 0.f, a0w = 0.f;   // head0, channels 4li+0..3
    float a1x = 0.f, a1y = 0.f, a1z = 0.f, a1w = 0.f;   // head1
    if (grp == 0) {
        uint4 hu = *(const uint4*)&h1b[(size_t)v * 64 + li * 4];
        a0x = ps0 * bl(hu.x); a1x = ps1 * bh(hu.x);
        a0y = ps0 * bl(hu.y); a1y = ps1 * bh(hu.y);
        a0z = ps0 * bl(hu.z); a1z = ps1 * bh(hu.z);
        a0w = ps0 * bl(hu.w); a1w = ps1 * bh(hu.w);
    }
    float s0l = 0.f, s1l = 0.f;

    int t0 = row_start[v], t1 = row_start[v + 1];
    for (int t = t0; t < t1; t += 64) {
        int nv = t1 - t; if (nv > 64) nv = 64;
        int srcn = v;
        float p0 = 0.f, p1 = 0.f;
        if (lane < nv) {
            srcn = csr_src[t + lane];
            float2 as = as1[srcn];
            p0 = __expf(leaky(as.x + ad.x) - m0);
            p1 = __expf(leaky(as.y + ad.y) - m1);
        }
        s0l += p0; s1l += p1;
        int pk = (int)__builtin_bit_cast(unsigned, __floats2half2_rn(p0, p1));
        int jmax = (nv + 3) >> 2;
        for (int j = 0; j < jmax; ++j) {
            int idx = 4 * j + grp;
            int sj = __shfl(srcn, idx);
            __half2 hp = __builtin_bit_cast(__half2, (unsigned)__shfl(pk, idx));
            float w0 = __half2float(__low2half(hp));
            float w1 = __half2float(__high2half(hp));
            uint4 hu = *(const uint4*)&h1b[(size_t)sj * 64 + li * 4];
            a0x = fmaf(w0, bl(hu.x), a0x); a1x = fmaf(w1, bh(hu.x), a1x);
            a0y = fmaf(w0, bl(hu.y), a0y); a1y = fmaf(w1, bh(hu.y), a1y);
            a0z = fmaf(w0, bl(hu.z), a0z); a1z = fmaf(w1, bh(hu.z), a1z);
            a0w = fmaf(w0, bl(hu.w), a0w); a1w = fmaf(w1, bh(hu.w), a1w);
        }
    }
    // sum s over all 64 lanes (masked lanes contributed 0)
#pragma unroll
    for (int off = 32; off >= 1; off >>= 1) {
        s0l += __shfl_xor(s0l, off);
        s1l += __shfl_xor(s1l, off);
    }
    float inv0 = 1.f / (s0l + ps0 + 1e-16f);
    float inv1 = 1.f / (s1l + ps1 + 1e-16f);
    // sum accumulators across the 4 edge-groups (lanes stride 16)
#pragma unroll
    for (int off = 16; off <= 32; off <<= 1) {
        a0x += __shfl_xor(a0x, off); a1x += __shfl_xor(a1x, off);
        a0y += __shfl_xor(a0y, off); a1y += __shfl_xor(a1y, off);
        a0z += __shfl_xor(a0z, off); a1z += __shfl_xor(a1z, off);
        a0w += __shfl_xor(a0w, off); a1w += __shfl_xor(a1w, off);
    }
    const float4 b0v = *(const float4*)&b1[4 * li];
    const float4 b1v = *(const float4*)&b1[64 + 4 * li];
    const float4 w0v = *(const float4*)&W2[4 * li];
    const float4 w1v = *(const float4*)&W2[64 + 4 * li];
    float o;
    float hv = 0.f;
    o = fmaxf(fmaf(a0x, inv0, b0v.x), 0.f); hv = fmaf(o, w0v.x, hv);
    o = fmaxf(fmaf(a0y, inv0, b0v.y), 0.f); hv = fmaf(o, w0v.y, hv);
    o = fmaxf(fmaf(a0z, inv0, b0v.z), 0.f); hv = fmaf(o, w0v.z, hv);
    o = fmaxf(fmaf(a0w, inv0, b0v.w), 0.f); hv = fmaf(o, w0v.w, hv);
    o = fmaxf(fmaf(a1x, inv1, b1v.x), 0.f); hv = fmaf(o, w1v.x, hv);
    o = fmaxf(fmaf(a1y, inv1, b1v.y), 0.f); hv = fmaf(o, w1v.y, hv);
    o = fmaxf(fmaf(a1z, inv1, b1v.z), 0.f); hv = fmaf(o, w1v.z, hv);
    o = fmaxf(fmaf(a1w, inv1, b1v.w), 0.f); hv = fmaf(o, w1v.w, hv);
#pragma unroll
    for (int off = 1; off <= 8; off <<= 1) hv += __shfl_xor(hv, off);
    if (lane == 0) h2[v] = hv;
}

// ---------------------------------------------------------------------------
// Layer-2 gather: one thread per node, online softmax + sigmoid (proven v2).
// ---------------------------------------------------------------------------
__global__ void gather2_kernel(
    const float* __restrict__ h2, const int* __restrict__ row_start, const int* __restrict__ csr_src,
    const float* __restrict__ aS2, const float* __restrict__ aD2, const float* __restrict__ b2,
    float* __restrict__ out, int n)
{
    int v = blockIdx.x * 256 + threadIdx.x;
    if (v >= n) return;
    float as2 = aS2[0], ad2c = aD2[0];
    float hv = h2[v];
    float ad = hv * ad2c;
    float e = leaky(fmaf(hv, as2, ad));
    float m = e, s = 1.f, num = hv;
    int t1 = row_start[v + 1];
    for (int t = row_start[v]; t < t1; ++t) {
        float hsv = h2[csr_src[t]];
        float en = leaky(fmaf(hsv, as2, ad));
        if (en > m) { float c = __expf(m - en); s *= c; num *= c; m = en; }
        float p = __expf(en - m);
        s += p;
        num = fmaf(p, hsv, num);
    }
    float o = num / (s + 1e-16f) + b2[0];
    out[v] = 1.f / (1.f + __expf(-o));
}

// ---------------------------------------------------------------------------
extern "C" void kernel_launch(void* const* d_in, const int* in_sizes, int n_in,
                              void* d_out, int out_size, void* d_ws, size_t ws_size,
                              hipStream_t stream)
{
    const float* x      = (const float*)d_in[0];
    const int*   eidx   = (const int*)  d_in[1];
    const float* W1     = (const float*)d_in[2];
    const float* a_src1 = (const float*)d_in[3];
    const float* a_dst1 = (const float*)d_in[4];
    const float* b1     = (const float*)d_in[5];
    const float* W2     = (const float*)d_in[6];
    const float* a_src2 = (const float*)d_in[7];
    const float* a_dst2 = (const float*)d_in[8];
    const float* b2     = (const float*)d_in[9];

    int n = in_sizes[0] / 128;
    int E = in_sizes[1] / 2;
    const int* src = eidx;
    const int* dst = eidx + E;

    int NC = (E + CHUNK - 1) / CHUNK;   // 196 for E=1.6M
    int NB = (n + 255) / 256;           // 196 for n=50000 (<=256 required)

    char* ws = (char*)d_ws;
    size_t off = 0;
    auto alloc = [&](size_t bytes) { size_t o = off; off += (bytes + 255) & ~(size_t)255; return o; };

    unsigned* h1b   = (unsigned*)(ws + alloc((size_t)n * 64 * 4));   // 12.8 MB
    float2* as1     = (float2*)(ws + alloc((size_t)n * 8));
    float2* ad1     = (float2*)(ws + alloc((size_t)n * 8));
    float*  h2      = (float*) (ws + alloc((size_t)n * 4));
    int*    rowst   = (int*)   (ws + alloc((size_t)(n + 1) * 4));
    unsigned* keys  = (unsigned*)(ws + alloc(256));                  // [as0max, as1max]
    int*    osc     = (int*)   (ws + alloc((size_t)NB * NC * 4));    // 153 KB
    int2*   pairs   = (int2*)  (ws + alloc((size_t)E * 8));          // 12.8 MB
    int*    csr_src = (int*)   (ws + alloc((size_t)E * 4));          // 6.4 MB
    (void)ws_size; (void)n_in; (void)out_size;

    hipMemsetAsync(keys, 0x00, 8, stream);   // max slots -> smallest key

    gemm1_kernel<<<1024, 256, 0, stream>>>(x, W1, a_src1, a_dst1, h1b, as1, ad1, keys, n);

    chist_kernel<<<NC, 256, 0, stream>>>(dst, E, NB, NC, osc);
    oscan_kernel<<<1, 1024, 0, stream>>>(osc, NB * NC);
    cscatter_kernel<<<NC, 256, 0, stream>>>(src, dst, E, NB, NC, osc, pairs);
    fsort_kernel<<<NB, 256, 0, stream>>>(pairs, osc, E, n, NB, NC, rowst, csr_src);

    gather1_kernel<<<(n + 3) / 4, 256, 0, stream>>>(h1b, as1, ad1, rowst, csr_src, b1, W2,
                                                    keys, h2, n);
    gather2_kernel<<<(n + 255) / 256, 256, 0, stream>>>(h2, rowst, csr_src, a_src2, a_dst2, b2,
                                                        (float*)d_out, n);
}

// Round 14
// 341.314 us; speedup vs baseline: 4.2440x; 1.0154x over previous
//
#include <hip/hip_runtime.h>
#include <hip/hip_bf16.h>
#include <hip/hip_fp16.h>

#define LEAKY_SLOPE 0.2f

typedef __attribute__((ext_vector_type(8))) short bf16x8;
typedef __attribute__((ext_vector_type(4))) float f32x4;

__device__ __forceinline__ float leaky(float x) { return x > 0.f ? x : LEAKY_SLOPE * x; }

// monotone float<->uint key map (order-preserving for atomicMax on unsigned)
__device__ __forceinline__ unsigned fkey(float f)
{
    unsigned u = __float_as_uint(f);
    return (u & 0x80000000u) ? ~u : (u | 0x80000000u);
}
__device__ __forceinline__ float key_to_float(unsigned k)
{
    unsigned u = (k & 0x80000000u) ? (k & 0x7fffffffu) : ~k;
    return __uint_as_float(u);
}

// bf16-pair unpack: low16 -> head0, high16 -> head1
__device__ __forceinline__ float bl(unsigned u) { return __uint_as_float(u << 16); }
__device__ __forceinline__ float bh(unsigned u) { return __uint_as_float(u & 0xffff0000u); }

// round-to-nearest-even bf16 packing: lo -> low 16 bits, hi -> high 16 bits
__device__ __forceinline__ unsigned pack_bf16_pair(float lo, float hi)
{
    unsigned blv = __float_as_uint(lo);
    blv = (blv + 0x7fffu + ((blv >> 16) & 1u)) >> 16;
    unsigned bhv = __float_as_uint(hi);
    bhv = (bhv + 0x7fffu + ((bhv >> 16) & 1u)) & 0xffff0000u;
    return blv | bhv;
}

// ---------------------------------------------------------------------------
// wtilde: w~[k][{s0,s1,d0,d1}] = per-head dot of W1 row k with a_src/a_dst.
// alpha = x @ w~  ==  sum_c h[c]*a[c]  (exact f32, associativity shuffled).
// ---------------------------------------------------------------------------
__global__ __launch_bounds__(256) void wtilde_kernel(
    const float* __restrict__ W1, const float* __restrict__ a_s, const float* __restrict__ a_d,
    float* __restrict__ wt)
{
    int w = threadIdx.x >> 6, l = threadIdx.x & 63;
    float as_l = a_s[l], as_h = a_s[64 + l];
    float ad_l = a_d[l], ad_h = a_d[64 + l];
    for (int i = 0; i < 16; ++i) {
        int k = blockIdx.x * 64 + w * 16 + i;
        const float* wr = W1 + (size_t)k * 128;
        float w_lo = wr[l], w_hi = wr[64 + l];
        float s0 = w_lo * as_l, s1 = w_hi * as_h;
        float d0 = w_lo * ad_l, d1 = w_hi * ad_h;
#pragma unroll
        for (int off = 32; off >= 1; off >>= 1) {
            s0 += __shfl_xor(s0, off);
            s1 += __shfl_xor(s1, off);
            d0 += __shfl_xor(d0, off);
            d1 += __shfl_xor(d1, off);
        }
        if (l == 0) *(float4*)&wt[k * 4] = make_float4(s0, s1, d0, d1);
    }
}

// ---------------------------------------------------------------------------
// alpha: exact f32 per-node logit pieces; block-local max -> 2 atomics/block
// on keys[0..1] (write-only; later kernels only read -> no contention).
// ---------------------------------------------------------------------------
__global__ __launch_bounds__(256) void alpha_kernel(
    const float* __restrict__ x, const float* __restrict__ wt,
    float2* __restrict__ as1, float2* __restrict__ ad1,
    unsigned* __restrict__ keys, int n)
{
    __shared__ float wtl[512];
    __shared__ float m0s[4], m1s[4];
    int tid = threadIdx.x;
    for (int i = tid; i < 512; i += 256) wtl[i] = wt[i];
    __syncthreads();
    int w = tid >> 6, l = tid & 63;
    const float4 wa = *(const float4*)&wtl[l * 4];
    const float4 wb = *(const float4*)&wtl[(64 + l) * 4];
    float rm0 = -INFINITY, rm1 = -INFINITY;
    for (int v = blockIdx.x * 4 + w; v < n; v += gridDim.x * 4) {
        const float* xr = x + (size_t)v * 128;
        float xa = xr[l], xb2 = xr[64 + l];
        float s0 = fmaf(xa, wa.x, xb2 * wb.x);
        float s1 = fmaf(xa, wa.y, xb2 * wb.y);
        float d0 = fmaf(xa, wa.z, xb2 * wb.z);
        float d1 = fmaf(xa, wa.w, xb2 * wb.w);
#pragma unroll
        for (int off = 32; off >= 1; off >>= 1) {
            s0 += __shfl_xor(s0, off);
            s1 += __shfl_xor(s1, off);
            d0 += __shfl_xor(d0, off);
            d1 += __shfl_xor(d1, off);
        }
        if (l == 0) {
            as1[v] = make_float2(s0, s1);
            ad1[v] = make_float2(d0, d1);
            rm0 = fmaxf(rm0, s0);
            rm1 = fmaxf(rm1, s1);
        }
    }
    if (l == 0) { m0s[w] = rm0; m1s[w] = rm1; }
    __syncthreads();
    if (tid == 0) {
        float m0 = fmaxf(fmaxf(m0s[0], m0s[1]), fmaxf(m0s[2], m0s[3]));
        float m1 = fmaxf(fmaxf(m1s[0], m1s[1]), fmaxf(m1s[2], m1s[3]));
        atomicMax(&keys[0], fkey(m0));
        atomicMax(&keys[1], fkey(m1));
    }
}

// ---------------------------------------------------------------------------
// MFMA GEMM: h1 = bf16(x) @ bf16(W1), f32 accum, packed-bf16 store.
// 64-node tile/block, 4 waves, 8 N-tiles x 4 K-steps of 16x16x32 bf16.
// LDS tiles XOR-swizzled (idx ^= (row&7)<<3) to kill ds_read_b128 conflicts.
// C/D layout (verified): col = lane&15, row = (lane>>4)*4 + reg.
// ---------------------------------------------------------------------------
__global__ __launch_bounds__(256) void gemm_mfma_kernel(
    const float* __restrict__ x, const float* __restrict__ W1,
    unsigned* __restrict__ h1b, int n)
{
    __shared__ unsigned short wl[128 * 128];   // W1^T bf16, [j][k], 32 KB
    __shared__ unsigned short xl[64 * 128];    // x-tile bf16, [row][k], 16 KB
    int tid = threadIdx.x;
    int base = blockIdx.x * 64;

    // stage W1 transposed: read f32 [k][j] coalesced, write bf16 pair (k,k+1)
    for (int f = tid; f < 8192; f += 256) {
        int j = f & 127, k = (f >> 7) * 2;
        float w0 = W1[(size_t)k * 128 + j];
        float w1 = W1[(size_t)(k + 1) * 128 + j];
        *(unsigned*)&wl[j * 128 + (k ^ ((j & 7) << 3))] = pack_bf16_pair(w0, w1);
    }
    // stage x-tile: read float2 coalesced, write bf16 pair
    for (int f = tid; f < 4096; f += 256) {
        int row = f >> 6, k = (f & 63) * 2;
        int node = base + row;
        float2 xv = make_float2(0.f, 0.f);
        if (node < n) xv = *(const float2*)&x[(size_t)node * 128 + k];
        *(unsigned*)&xl[row * 128 + (k ^ ((row & 7) << 3))] = pack_bf16_pair(xv.x, xv.y);
    }
    __syncthreads();

    int w = tid >> 6, l = tid & 63;
    int ar = w * 16 + (l & 15);      // A row within block tile
    int kq = (l >> 4) * 8;           // k-quarter offset

    bf16x8 A[4];
#pragma unroll
    for (int kk = 0; kk < 4; ++kk)
        A[kk] = *(const bf16x8*)&xl[ar * 128 + ((kk * 32 + kq) ^ ((ar & 7) << 3))];

    f32x4 acc[8];
#pragma unroll
    for (int t = 0; t < 8; ++t) acc[t] = (f32x4){0.f, 0.f, 0.f, 0.f};

#pragma unroll
    for (int t = 0; t < 8; ++t) {
        int br = t * 16 + (l & 15);
#pragma unroll
        for (int kk = 0; kk < 4; ++kk) {
            bf16x8 B = *(const bf16x8*)&wl[br * 128 + ((kk * 32 + kq) ^ ((br & 7) << 3))];
            acc[t] = __builtin_amdgcn_mfma_f32_16x16x32_bf16(A[kk], B, acc[t], 0, 0, 0);
        }
    }

    // store packed {head0=col c, head1=col 64+c}: c = (l&15) + 16t, t=0..3
#pragma unroll
    for (int r = 0; r < 4; ++r) {
        int nd = base + w * 16 + (l >> 4) * 4 + r;
        if (nd < n) {
#pragma unroll
            for (int t = 0; t < 4; ++t)
                h1b[(size_t)nd * 64 + (l & 15) + 16 * t] =
                    pack_bf16_pair(acc[t][r], acc[t + 4][r]);
        }
    }
}

// ---------------------------------------------------------------------------
// CSR build via two-level counting sort (unchanged).
// ---------------------------------------------------------------------------
#define CHUNK 8192

__global__ __launch_bounds__(256) void chist_kernel(
    const int* __restrict__ dst, int E, int NB, int NC, int* __restrict__ osc)
{
    __shared__ int h[256];
    int tid = threadIdx.x, c = blockIdx.x;
    h[tid] = 0;
    __syncthreads();
    int e0 = c * CHUNK, e1 = min(e0 + CHUNK, E);
    for (int e = e0 + tid; e < e1; e += 256)
        atomicAdd(&h[dst[e] >> 8], 1);
    __syncthreads();
    if (tid < NB) osc[tid * NC + c] = h[tid];
}

__global__ __launch_bounds__(1024) void oscan_kernel(int* __restrict__ osc, int len)
{
    __shared__ int wsum[16];
    int tid = threadIdx.x;
    int seg = (len + 1023) / 1024;
    int st = tid * seg, en = min(st + seg, len);
    int s = 0;
    for (int i = st; i < en; ++i) s += osc[i];
    int lane = tid & 63, w = tid >> 6;
    int incl = s;
#pragma unroll
    for (int off = 1; off < 64; off <<= 1) {
        int t = __shfl_up(incl, off);
        if (lane >= off) incl += t;
    }
    if (lane == 63) wsum[w] = incl;
    __syncthreads();
    int wb = 0;
    for (int i = 0; i < w; ++i) wb += wsum[i];
    int run = wb + incl - s;
    for (int i = st; i < en; ++i) { int v = osc[i]; osc[i] = run; run += v; }
}

__global__ __launch_bounds__(256) void cscatter_kernel(
    const int* __restrict__ src, const int* __restrict__ dst,
    int E, int NB, int NC, const int* __restrict__ osc, int2* __restrict__ pairs)
{
    __shared__ int cur[256];
    int tid = threadIdx.x, c = blockIdx.x;
    if (tid < NB) cur[tid] = osc[tid * NC + c];
    __syncthreads();
    int e0 = c * CHUNK, e1 = min(e0 + CHUNK, E);
    for (int e = e0 + tid; e < e1; e += 256) {
        int d = dst[e];
        int p = atomicAdd(&cur[d >> 8], 1);
        pairs[p] = make_int2(src[e], d);
    }
}

__global__ __launch_bounds__(256) void fsort_kernel(
    const int2* __restrict__ pairs, const int* __restrict__ osc,
    int E, int n, int NB, int NC,
    int* __restrict__ row_start, int* __restrict__ csr_src)
{
    __shared__ int fh[256];
    __shared__ int cur[256];
    __shared__ int wsum[4];
    int tid = threadIdx.x, b = blockIdx.x;
    int rbase = osc[b * NC];
    int rend  = (b + 1 < NB) ? osc[(b + 1) * NC] : E;
    fh[tid] = 0;
    __syncthreads();
    for (int i = rbase + tid; i < rend; i += 256)
        atomicAdd(&fh[pairs[i].y & 255], 1);
    __syncthreads();
    int v = fh[tid];
    int lane = tid & 63, w = tid >> 6;
    int incl = v;
#pragma unroll
    for (int off = 1; off < 64; off <<= 1) {
        int t = __shfl_up(incl, off);
        if (lane >= off) incl += t;
    }
    if (lane == 63) wsum[w] = incl;
    __syncthreads();
    int wb = 0;
    for (int i = 0; i < w; ++i) wb += wsum[i];
    int excl = wb + incl - v;
    int node = b * 256 + tid;
    if (node < n) row_start[node] = rbase + excl;
    cur[tid] = rbase + excl;
    __syncthreads();
    for (int i = rbase + tid; i < rend; i += 256) {
        int2 pr = pairs[i];
        int p = atomicAdd(&cur[pr.y & 255], 1);
        csr_src[p] = pr.x;
    }
    if (b == 0 && tid == 0) row_start[n] = E;
}

// ---------------------------------------------------------------------------
// Layer-1 gather v4 (unchanged): bound-softmax, keys read-only, no atomics.
// ---------------------------------------------------------------------------
__global__ __launch_bounds__(256) void gather1_kernel(
    const unsigned* __restrict__ h1b, const float2* __restrict__ as1, const float2* __restrict__ ad1,
    const int* __restrict__ row_start, const int* __restrict__ csr_src,
    const float* __restrict__ b1, const float* __restrict__ W2,
    const unsigned* __restrict__ keys, float* __restrict__ h2, int n)
{
    int wid = threadIdx.x >> 6, lane = threadIdx.x & 63;
    int v = blockIdx.x * 4 + wid;
    if (v >= n) return;
    int grp = lane >> 4, li = lane & 15;

    float gm0 = key_to_float(keys[0]);
    float gm1 = key_to_float(keys[1]);

    float2 ad = ad1[v];
    float2 asv = as1[v];
    float m0 = leaky(gm0 + ad.x), m1 = leaky(gm1 + ad.y);
    float ps0 = __expf(leaky(asv.x + ad.x) - m0);   // self-loop weight
    float ps1 = __expf(leaky(asv.y + ad.y) - m1);

    float a0x = 0.f, a0y = 0.f, a0z = 0.f, a0w = 0.f;   // head0, channels 4li+0..3
    float a1x = 0.f, a1y = 0.f, a1z = 0.f, a1w = 0.f;   // head1
    if (grp == 0) {
        uint4 hu = *(const uint4*)&h1b[(size_t)v * 64 + li * 4];
        a0x = ps0 * bl(hu.x); a1x = ps1 * bh(hu.x);
        a0y = ps0 * bl(hu.y); a1y = ps1 * bh(hu.y);
        a0z = ps0 * bl(hu.z); a1z = ps1 * bh(hu.z);
        a0w = ps0 * bl(hu.w); a1w = ps1 * bh(hu.w);
    }
    float s0l = 0.f, s1l = 0.f;

    int t0 = row_start[v], t1 = row_start[v + 1];
    for (int t = t0; t < t1; t += 64) {
        int nv = t1 - t; if (nv > 64) nv = 64;
        int srcn = v;
        float p0 = 0.f, p1 = 0.f;
        if (lane < nv) {
            srcn = csr_src[t + lane];
            float2 as = as1[srcn];
            p0 = __expf(leaky(as.x + ad.x) - m0);
            p1 = __expf(leaky(as.y + ad.y) - m1);
        }
        s0l += p0; s1l += p1;
        int pk = (int)__builtin_bit_cast(unsigned, __floats2half2_rn(p0, p1));
        int jmax = (nv + 3) >> 2;
        for (int j = 0; j < jmax; ++j) {
            int idx = 4 * j + grp;
            int sj = __shfl(srcn, idx);
            __half2 hp = __builtin_bit_cast(__half2, (unsigned)__shfl(pk, idx));
            float w0 = __half2float(__low2half(hp));
            float w1 = __half2float(__high2half(hp));
            uint4 hu = *(const uint4*)&h1b[(size_t)sj * 64 + li * 4];
            a0x = fmaf(w0, bl(hu.x), a0x); a1x = fmaf(w1, bh(hu.x), a1x);
            a0y = fmaf(w0, bl(hu.y), a0y); a1y = fmaf(w1, bh(hu.y), a1y);
            a0z = fmaf(w0, bl(hu.z), a0z); a1z = fmaf(w1, bh(hu.z), a1z);
            a0w = fmaf(w0, bl(hu.w), a0w); a1w = fmaf(w1, bh(hu.w), a1w);
        }
    }
#pragma unroll
    for (int off = 32; off >= 1; off >>= 1) {
        s0l += __shfl_xor(s0l, off);
        s1l += __shfl_xor(s1l, off);
    }
    float inv0 = 1.f / (s0l + ps0 + 1e-16f);
    float inv1 = 1.f / (s1l + ps1 + 1e-16f);
#pragma unroll
    for (int off = 16; off <= 32; off <<= 1) {
        a0x += __shfl_xor(a0x, off); a1x += __shfl_xor(a1x, off);
        a0y += __shfl_xor(a0y, off); a1y += __shfl_xor(a1y, off);
        a0z += __shfl_xor(a0z, off); a1z += __shfl_xor(a1z, off);
        a0w += __shfl_xor(a0w, off); a1w += __shfl_xor(a1w, off);
    }
    const float4 b0v = *(const float4*)&b1[4 * li];
    const float4 b1v = *(const float4*)&b1[64 + 4 * li];
    const float4 w0v = *(const float4*)&W2[4 * li];
    const float4 w1v = *(const float4*)&W2[64 + 4 * li];
    float o;
    float hv = 0.f;
    o = fmaxf(fmaf(a0x, inv0, b0v.x), 0.f); hv = fmaf(o, w0v.x, hv);
    o = fmaxf(fmaf(a0y, inv0, b0v.y), 0.f); hv = fmaf(o, w0v.y, hv);
    o = fmaxf(fmaf(a0z, inv0, b0v.z), 0.f); hv = fmaf(o, w0v.z, hv);
    o = fmaxf(fmaf(a0w, inv0, b0v.w), 0.f); hv = fmaf(o, w0v.w, hv);
    o = fmaxf(fmaf(a1x, inv1, b1v.x), 0.f); hv = fmaf(o, w1v.x, hv);
    o = fmaxf(fmaf(a1y, inv1, b1v.y), 0.f); hv = fmaf(o, w1v.y, hv);
    o = fmaxf(fmaf(a1z, inv1, b1v.z), 0.f); hv = fmaf(o, w1v.z, hv);
    o = fmaxf(fmaf(a1w, inv1, b1v.w), 0.f); hv = fmaf(o, w1v.w, hv);
#pragma unroll
    for (int off = 1; off <= 8; off <<= 1) hv += __shfl_xor(hv, off);
    if (lane == 0) h2[v] = hv;
}

// ---------------------------------------------------------------------------
// Layer-2 gather (unchanged): one thread per node, online softmax + sigmoid.
// ---------------------------------------------------------------------------
__global__ void gather2_kernel(
    const float* __restrict__ h2, const int* __restrict__ row_start, const int* __restrict__ csr_src,
    const float* __restrict__ aS2, const float* __restrict__ aD2, const float* __restrict__ b2,
    float* __restrict__ out, int n)
{
    int v = blockIdx.x * 256 + threadIdx.x;
    if (v >= n) return;
    float as2 = aS2[0], ad2c = aD2[0];
    float hv = h2[v];
    float ad = hv * ad2c;
    float e = leaky(fmaf(hv, as2, ad));
    float m = e, s = 1.f, num = hv;
    int t1 = row_start[v + 1];
    for (int t = row_start[v]; t < t1; ++t) {
        float hsv = h2[csr_src[t]];
        float en = leaky(fmaf(hsv, as2, ad));
        if (en > m) { float c = __expf(m - en); s *= c; num *= c; m = en; }
        float p = __expf(en - m);
        s += p;
        num = fmaf(p, hsv, num);
    }
    float o = num / (s + 1e-16f) + b2[0];
    out[v] = 1.f / (1.f + __expf(-o));
}

// ---------------------------------------------------------------------------
extern "C" void kernel_launch(void* const* d_in, const int* in_sizes, int n_in,
                              void* d_out, int out_size, void* d_ws, size_t ws_size,
                              hipStream_t stream)
{
    const float* x      = (const float*)d_in[0];
    const int*   eidx   = (const int*)  d_in[1];
    const float* W1     = (const float*)d_in[2];
    const float* a_src1 = (const float*)d_in[3];
    const float* a_dst1 = (const float*)d_in[4];
    const float* b1     = (const float*)d_in[5];
    const float* W2     = (const float*)d_in[6];
    const float* a_src2 = (const float*)d_in[7];
    const float* a_dst2 = (const float*)d_in[8];
    const float* b2     = (const float*)d_in[9];

    int n = in_sizes[0] / 128;
    int E = in_sizes[1] / 2;
    const int* src = eidx;
    const int* dst = eidx + E;

    int NC = (E + CHUNK - 1) / CHUNK;   // 196 for E=1.6M
    int NB = (n + 255) / 256;           // 196 for n=50000 (<=256 required)

    char* ws = (char*)d_ws;
    size_t off = 0;
    auto alloc = [&](size_t bytes) { size_t o = off; off += (bytes + 255) & ~(size_t)255; return o; };

    unsigned* h1b   = (unsigned*)(ws + alloc((size_t)n * 64 * 4));   // 12.8 MB
    float2* as1     = (float2*)(ws + alloc((size_t)n * 8));
    float2* ad1     = (float2*)(ws + alloc((size_t)n * 8));
    float*  h2      = (float*) (ws + alloc((size_t)n * 4));
    int*    rowst   = (int*)   (ws + alloc((size_t)(n + 1) * 4));
    unsigned* keys  = (unsigned*)(ws + alloc(256));                  // [as0max, as1max]
    float*  wt      = (float*) (ws + alloc(512 * 4));                // w~[128][4]
    int*    osc     = (int*)   (ws + alloc((size_t)NB * NC * 4));    // 153 KB
    int2*   pairs   = (int2*)  (ws + alloc((size_t)E * 8));          // 12.8 MB
    int*    csr_src = (int*)   (ws + alloc((size_t)E * 4));          // 6.4 MB
    (void)ws_size; (void)n_in; (void)out_size;

    hipMemsetAsync(keys, 0x00, 8, stream);   // max slots -> smallest key

    wtilde_kernel<<<2, 256, 0, stream>>>(W1, a_src1, a_dst1, wt);
    alpha_kernel<<<1024, 256, 0, stream>>>(x, wt, as1, ad1, keys, n);
    gemm_mfma_kernel<<<(n + 63) / 64, 256, 0, stream>>>(x, W1, h1b, n);

    chist_kernel<<<NC, 256, 0, stream>>>(dst, E, NB, NC, osc);
    oscan_kernel<<<1, 1024, 0, stream>>>(osc, NB * NC);
    cscatter_kernel<<<NC, 256, 0, stream>>>(src, dst, E, NB, NC, osc, pairs);
    fsort_kernel<<<NB, 256, 0, stream>>>(pairs, osc, E, n, NB, NC, rowst, csr_src);

    gather1_kernel<<<(n + 3) / 4, 256, 0, stream>>>(h1b, as1, ad1, rowst, csr_src, b1, W2,
                                                    keys, h2, n);
    gather2_kernel<<<(n + 255) / 256, 256, 0, stream>>>(h2, rowst, csr_src, a_src2, a_dst2, b2,
                                                        (float*)d_out, n);
}

// Round 16
// 327.485 us; speedup vs baseline: 4.4232x; 1.0422x over previous
//
#include <hip/hip_runtime.h>
#include <hip/hip_bf16.h>
#include <hip/hip_fp16.h>

#define LEAKY_SLOPE 0.2f

typedef __attribute__((ext_vector_type(8))) short bf16x8;
typedef __attribute__((ext_vector_type(4))) float f32x4;

__device__ __forceinline__ float leaky(float x) { return x > 0.f ? x : LEAKY_SLOPE * x; }

// monotone float<->uint key map (order-preserving for atomicMax on unsigned)
__device__ __forceinline__ unsigned fkey(float f)
{
    unsigned u = __float_as_uint(f);
    return (u & 0x80000000u) ? ~u : (u | 0x80000000u);
}
__device__ __forceinline__ float key_to_float(unsigned k)
{
    unsigned u = (k & 0x80000000u) ? (k & 0x7fffffffu) : ~k;
    return __uint_as_float(u);
}

// bf16-pair unpack: low16 -> head0, high16 -> head1
__device__ __forceinline__ float bl(unsigned u) { return __uint_as_float(u << 16); }
__device__ __forceinline__ float bh(unsigned u) { return __uint_as_float(u & 0xffff0000u); }

// round-to-nearest-even bf16 packing: lo -> low 16 bits, hi -> high 16 bits
__device__ __forceinline__ unsigned pack_bf16_pair(float lo, float hi)
{
    unsigned blv = __float_as_uint(lo);
    blv = (blv + 0x7fffu + ((blv >> 16) & 1u)) >> 16;
    unsigned bhv = __float_as_uint(hi);
    bhv = (bhv + 0x7fffu + ((bhv >> 16) & 1u)) & 0xffff0000u;
    return blv | bhv;
}

// ---------------------------------------------------------------------------
// wtilde: w~[k][{s0,s1,d0,d1}] = per-head dot of W1 row k with a_src/a_dst.
// ---------------------------------------------------------------------------
__global__ __launch_bounds__(256) void wtilde_kernel(
    const float* __restrict__ W1, const float* __restrict__ a_s, const float* __restrict__ a_d,
    float* __restrict__ wt)
{
    int w = threadIdx.x >> 6, l = threadIdx.x & 63;
    float as_l = a_s[l], as_h = a_s[64 + l];
    float ad_l = a_d[l], ad_h = a_d[64 + l];
    for (int i = 0; i < 16; ++i) {
        int k = blockIdx.x * 64 + w * 16 + i;
        const float* wr = W1 + (size_t)k * 128;
        float w_lo = wr[l], w_hi = wr[64 + l];
        float s0 = w_lo * as_l, s1 = w_hi * as_h;
        float d0 = w_lo * ad_l, d1 = w_hi * ad_h;
#pragma unroll
        for (int off = 32; off >= 1; off >>= 1) {
            s0 += __shfl_xor(s0, off);
            s1 += __shfl_xor(s1, off);
            d0 += __shfl_xor(d0, off);
            d1 += __shfl_xor(d1, off);
        }
        if (l == 0) *(float4*)&wt[k * 4] = make_float4(s0, s1, d0, d1);
    }
}

// ---------------------------------------------------------------------------
// alpha: exact f32 per-node logit pieces; block-local max -> 2 atomics/block
// on keys[0..1] (write-only; later kernels only read -> no contention).
// ---------------------------------------------------------------------------
__global__ __launch_bounds__(256) void alpha_kernel(
    const float* __restrict__ x, const float* __restrict__ wt,
    float2* __restrict__ as1, float2* __restrict__ ad1,
    unsigned* __restrict__ keys, int n)
{
    __shared__ float wtl[512];
    __shared__ float m0s[4], m1s[4];
    int tid = threadIdx.x;
    for (int i = tid; i < 512; i += 256) wtl[i] = wt[i];
    __syncthreads();
    int w = tid >> 6, l = tid & 63;
    const float4 wa = *(const float4*)&wtl[l * 4];
    const float4 wb = *(const float4*)&wtl[(64 + l) * 4];
    float rm0 = -INFINITY, rm1 = -INFINITY;
    for (int v = blockIdx.x * 4 + w; v < n; v += gridDim.x * 4) {
        const float* xr = x + (size_t)v * 128;
        float xa = xr[l], xb2 = xr[64 + l];
        float s0 = fmaf(xa, wa.x, xb2 * wb.x);
        float s1 = fmaf(xa, wa.y, xb2 * wb.y);
        float d0 = fmaf(xa, wa.z, xb2 * wb.z);
        float d1 = fmaf(xa, wa.w, xb2 * wb.w);
#pragma unroll
        for (int off = 32; off >= 1; off >>= 1) {
            s0 += __shfl_xor(s0, off);
            s1 += __shfl_xor(s1, off);
            d0 += __shfl_xor(d0, off);
            d1 += __shfl_xor(d1, off);
        }
        if (l == 0) {
            as1[v] = make_float2(s0, s1);
            ad1[v] = make_float2(d0, d1);
            rm0 = fmaxf(rm0, s0);
            rm1 = fmaxf(rm1, s1);
        }
    }
    if (l == 0) { m0s[w] = rm0; m1s[w] = rm1; }
    __syncthreads();
    if (tid == 0) {
        float m0 = fmaxf(fmaxf(m0s[0], m0s[1]), fmaxf(m0s[2], m0s[3]));
        float m1 = fmaxf(fmaxf(m1s[0], m1s[1]), fmaxf(m1s[2], m1s[3]));
        atomicMax(&keys[0], fkey(m0));
        atomicMax(&keys[1], fkey(m1));
    }
}

// ---------------------------------------------------------------------------
// MFMA GEMM: h1 = bf16(x) @ bf16(W1), f32 accum, packed-bf16 store (unchanged).
// ---------------------------------------------------------------------------
__global__ __launch_bounds__(256) void gemm_mfma_kernel(
    const float* __restrict__ x, const float* __restrict__ W1,
    unsigned* __restrict__ h1b, int n)
{
    __shared__ unsigned short wl[128 * 128];   // W1^T bf16, [j][k], 32 KB
    __shared__ unsigned short xl[64 * 128];    // x-tile bf16, [row][k], 16 KB
    int tid = threadIdx.x;
    int base = blockIdx.x * 64;

    for (int f = tid; f < 8192; f += 256) {
        int j = f & 127, k = (f >> 7) * 2;
        float w0 = W1[(size_t)k * 128 + j];
        float w1 = W1[(size_t)(k + 1) * 128 + j];
        *(unsigned*)&wl[j * 128 + (k ^ ((j & 7) << 3))] = pack_bf16_pair(w0, w1);
    }
    for (int f = tid; f < 4096; f += 256) {
        int row = f >> 6, k = (f & 63) * 2;
        int node = base + row;
        float2 xv = make_float2(0.f, 0.f);
        if (node < n) xv = *(const float2*)&x[(size_t)node * 128 + k];
        *(unsigned*)&xl[row * 128 + (k ^ ((row & 7) << 3))] = pack_bf16_pair(xv.x, xv.y);
    }
    __syncthreads();

    int w = tid >> 6, l = tid & 63;
    int ar = w * 16 + (l & 15);
    int kq = (l >> 4) * 8;

    bf16x8 A[4];
#pragma unroll
    for (int kk = 0; kk < 4; ++kk)
        A[kk] = *(const bf16x8*)&xl[ar * 128 + ((kk * 32 + kq) ^ ((ar & 7) << 3))];

    f32x4 acc[8];
#pragma unroll
    for (int t = 0; t < 8; ++t) acc[t] = (f32x4){0.f, 0.f, 0.f, 0.f};

#pragma unroll
    for (int t = 0; t < 8; ++t) {
        int br = t * 16 + (l & 15);
#pragma unroll
        for (int kk = 0; kk < 4; ++kk) {
            bf16x8 B = *(const bf16x8*)&wl[br * 128 + ((kk * 32 + kq) ^ ((br & 7) << 3))];
            acc[t] = __builtin_amdgcn_mfma_f32_16x16x32_bf16(A[kk], B, acc[t], 0, 0, 0);
        }
    }

#pragma unroll
    for (int r = 0; r < 4; ++r) {
        int nd = base + w * 16 + (l >> 4) * 4 + r;
        if (nd < n) {
#pragma unroll
            for (int t = 0; t < 4; ++t)
                h1b[(size_t)nd * 64 + (l & 15) + 16 * t] =
                    pack_bf16_pair(acc[t][r], acc[t + 4][r]);
        }
    }
}

// ---------------------------------------------------------------------------
// CSR build via two-level counting sort. pairs packed 32-bit:
//   pack = src (16b, n<65536) | (dst&255)<<16   (coarse bucket = dst>>8).
// ---------------------------------------------------------------------------
#define CHUNK 16384

__global__ __launch_bounds__(256) void chist_kernel(
    const int* __restrict__ dst, int E, int NB, int NC, int* __restrict__ osc)
{
    __shared__ int h[256];
    int tid = threadIdx.x, c = blockIdx.x;
    h[tid] = 0;
    __syncthreads();
    int e0 = c * CHUNK, e1 = min(e0 + CHUNK, E);
    for (int e = e0 + tid; e < e1; e += 256)
        atomicAdd(&h[dst[e] >> 8], 1);
    __syncthreads();
    if (tid < NB) osc[tid * NC + c] = h[tid];
}

__global__ __launch_bounds__(1024) void oscan_kernel(int* __restrict__ osc, int len)
{
    __shared__ int wsum[16];
    int tid = threadIdx.x;
    int seg = (len + 1023) / 1024;
    int st = tid * seg, en = min(st + seg, len);
    int s = 0;
    for (int i = st; i < en; ++i) s += osc[i];
    int lane = tid & 63, w = tid >> 6;
    int incl = s;
#pragma unroll
    for (int off = 1; off < 64; off <<= 1) {
        int t = __shfl_up(incl, off);
        if (lane >= off) incl += t;
    }
    if (lane == 63) wsum[w] = incl;
    __syncthreads();
    int wb = 0;
    for (int i = 0; i < w; ++i) wb += wsum[i];
    int run = wb + incl - s;
    for (int i = st; i < en; ++i) { int v = osc[i]; osc[i] = run; run += v; }
}

__global__ __launch_bounds__(256) void cscatter_kernel(
    const int* __restrict__ src, const int* __restrict__ dst,
    int E, int NB, int NC, const int* __restrict__ osc, unsigned* __restrict__ pairs)
{
    __shared__ int cur[256];
    int tid = threadIdx.x, c = blockIdx.x;
    if (tid < NB) cur[tid] = osc[tid * NC + c];
    __syncthreads();
    int e0 = c * CHUNK, e1 = min(e0 + CHUNK, E);
    for (int e = e0 + tid; e < e1; e += 256) {
        int d = dst[e];
        int p = atomicAdd(&cur[d >> 8], 1);
        pairs[p] = (unsigned)src[e] | ((unsigned)(d & 255) << 16);
    }
}

__global__ __launch_bounds__(256) void fsort_kernel(
    const unsigned* __restrict__ pairs, const int* __restrict__ osc,
    int E, int n, int NB, int NC,
    int* __restrict__ row_start, int* __restrict__ csr_src)
{
    __shared__ int fh[256];
    __shared__ int cur[256];
    __shared__ int wsum[4];
    int tid = threadIdx.x, b = blockIdx.x;
    int rbase = osc[b * NC];
    int rend  = (b + 1 < NB) ? osc[(b + 1) * NC] : E;
    fh[tid] = 0;
    __syncthreads();
    for (int i = rbase + tid; i < rend; i += 256)
        atomicAdd(&fh[(pairs[i] >> 16) & 255], 1);
    __syncthreads();
    int v = fh[tid];
    int lane = tid & 63, w = tid >> 6;
    int incl = v;
#pragma unroll
    for (int off = 1; off < 64; off <<= 1) {
        int t = __shfl_up(incl, off);
        if (lane >= off) incl += t;
    }
    if (lane == 63) wsum[w] = incl;
    __syncthreads();
    int wb = 0;
    for (int i = 0; i < w; ++i) wb += wsum[i];
    int excl = wb + incl - v;
    int node = b * 256 + tid;
    if (node < n) row_start[node] = rbase + excl;
    cur[tid] = rbase + excl;
    __syncthreads();
    for (int i = rbase + tid; i < rend; i += 256) {
        unsigned pr = pairs[i];
        int p = atomicAdd(&cur[(pr >> 16) & 255], 1);
        csr_src[p] = (int)(pr & 0xffffu);
    }
    if (b == 0 && tid == 0) row_start[n] = E;
}

// ---------------------------------------------------------------------------
// Layer-1 gather v4 (unchanged): bound-softmax, keys read-only, no atomics.
// ---------------------------------------------------------------------------
__global__ __launch_bounds__(256) void gather1_kernel(
    const unsigned* __restrict__ h1b, const float2* __restrict__ as1, const float2* __restrict__ ad1,
    const int* __restrict__ row_start, const int* __restrict__ csr_src,
    const float* __restrict__ b1, const float* __restrict__ W2,
    const unsigned* __restrict__ keys, float* __restrict__ h2, int n)
{
    int wid = threadIdx.x >> 6, lane = threadIdx.x & 63;
    int v = blockIdx.x * 4 + wid;
    if (v >= n) return;
    int grp = lane >> 4, li = lane & 15;

    float gm0 = key_to_float(keys[0]);
    float gm1 = key_to_float(keys[1]);

    float2 ad = ad1[v];
    float2 asv = as1[v];
    float m0 = leaky(gm0 + ad.x), m1 = leaky(gm1 + ad.y);
    float ps0 = __expf(leaky(asv.x + ad.x) - m0);   // self-loop weight
    float ps1 = __expf(leaky(asv.y + ad.y) - m1);

    float a0x = 0.f, a0y = 0.f, a0z = 0.f, a0w = 0.f;   // head0, channels 4li+0..3
    float a1x = 0.f, a1y = 0.f, a1z = 0.f, a1w = 0.f;   // head1
    if (grp == 0) {
        uint4 hu = *(const uint4*)&h1b[(size_t)v * 64 + li * 4];
        a0x = ps0 * bl(hu.x); a1x = ps1 * bh(hu.x);
        a0y = ps0 * bl(hu.y); a1y = ps1 * bh(hu.y);
        a0z = ps0 * bl(hu.z); a1z = ps1 * bh(hu.z);
        a0w = ps0 * bl(hu.w); a1w = ps1 * bh(hu.w);
    }
    float s0l = 0.f, s1l = 0.f;

    int t0 = row_start[v], t1 = row_start[v + 1];
    for (int t = t0; t < t1; t += 64) {
        int nv = t1 - t; if (nv > 64) nv = 64;
        int srcn = v;
        float p0 = 0.f, p1 = 0.f;
        if (lane < nv) {
            srcn = csr_src[t + lane];
            float2 as = as1[srcn];
            p0 = __expf(leaky(as.x + ad.x) - m0);
            p1 = __expf(leaky(as.y + ad.y) - m1);
        }
        s0l += p0; s1l += p1;
        int pk = (int)__builtin_bit_cast(unsigned, __floats2half2_rn(p0, p1));
        int jmax = (nv + 3) >> 2;
        for (int j = 0; j < jmax; ++j) {
            int idx = 4 * j + grp;
            int sj = __shfl(srcn, idx);
            __half2 hp = __builtin_bit_cast(__half2, (unsigned)__shfl(pk, idx));
            float w0 = __half2float(__low2half(hp));
            float w1 = __half2float(__high2half(hp));
            uint4 hu = *(const uint4*)&h1b[(size_t)sj * 64 + li * 4];
            a0x = fmaf(w0, bl(hu.x), a0x); a1x = fmaf(w1, bh(hu.x), a1x);
            a0y = fmaf(w0, bl(hu.y), a0y); a1y = fmaf(w1, bh(hu.y), a1y);
            a0z = fmaf(w0, bl(hu.z), a0z); a1z = fmaf(w1, bh(hu.z), a1z);
            a0w = fmaf(w0, bl(hu.w), a0w); a1w = fmaf(w1, bh(hu.w), a1w);
        }
    }
#pragma unroll
    for (int off = 32; off >= 1; off >>= 1) {
        s0l += __shfl_xor(s0l, off);
        s1l += __shfl_xor(s1l, off);
    }
    float inv0 = 1.f / (s0l + ps0 + 1e-16f);
    float inv1 = 1.f / (s1l + ps1 + 1e-16f);
#pragma unroll
    for (int off = 16; off <= 32; off <<= 1) {
        a0x += __shfl_xor(a0x, off); a1x += __shfl_xor(a1x, off);
        a0y += __shfl_xor(a0y, off); a1y += __shfl_xor(a1y, off);
        a0z += __shfl_xor(a0z, off); a1z += __shfl_xor(a1z, off);
        a0w += __shfl_xor(a0w, off); a1w += __shfl_xor(a1w, off);
    }
    const float4 b0v = *(const float4*)&b1[4 * li];
    const float4 b1v = *(const float4*)&b1[64 + 4 * li];
    const float4 w0v = *(const float4*)&W2[4 * li];
    const float4 w1v = *(const float4*)&W2[64 + 4 * li];
    float o;
    float hv = 0.f;
    o = fmaxf(fmaf(a0x, inv0, b0v.x), 0.f); hv = fmaf(o, w0v.x, hv);
    o = fmaxf(fmaf(a0y, inv0, b0v.y), 0.f); hv = fmaf(o, w0v.y, hv);
    o = fmaxf(fmaf(a0z, inv0, b0v.z), 0.f); hv = fmaf(o, w0v.z, hv);
    o = fmaxf(fmaf(a0w, inv0, b0v.w), 0.f); hv = fmaf(o, w0v.w, hv);
    o = fmaxf(fmaf(a1x, inv1, b1v.x), 0.f); hv = fmaf(o, w1v.x, hv);
    o = fmaxf(fmaf(a1y, inv1, b1v.y), 0.f); hv = fmaf(o, w1v.y, hv);
    o = fmaxf(fmaf(a1z, inv1, b1v.z), 0.f); hv = fmaf(o, w1v.z, hv);
    o = fmaxf(fmaf(a1w, inv1, b1v.w), 0.f); hv = fmaf(o, w1v.w, hv);
#pragma unroll
    for (int off = 1; off <= 8; off <<= 1) hv += __shfl_xor(hv, off);
    if (lane == 0) h2[v] = hv;
}

// ---------------------------------------------------------------------------
// Layer-2 gather (unchanged): one thread per node, online softmax + sigmoid.
// ---------------------------------------------------------------------------
__global__ void gather2_kernel(
    const float* __restrict__ h2, const int* __restrict__ row_start, const int* __restrict__ csr_src,
    const float* __restrict__ aS2, const float* __restrict__ aD2, const float* __restrict__ b2,
    float* __restrict__ out, int n)
{
    int v = blockIdx.x * 256 + threadIdx.x;
    if (v >= n) return;
    float as2 = aS2[0], ad2c = aD2[0];
    float hv = h2[v];
    float ad = hv * ad2c;
    float e = leaky(fmaf(hv, as2, ad));
    float m = e, s = 1.f, num = hv;
    int t1 = row_start[v + 1];
    for (int t = row_start[v]; t < t1; ++t) {
        float hsv = h2[csr_src[t]];
        float en = leaky(fmaf(hsv, as2, ad));
        if (en > m) { float c = __expf(m - en); s *= c; num *= c; m = en; }
        float p = __expf(en - m);
        s += p;
        num = fmaf(p, hsv, num);
    }
    float o = num / (s + 1e-16f) + b2[0];
    out[v] = 1.f / (1.f + __expf(-o));
}

// ---------------------------------------------------------------------------
extern "C" void kernel_launch(void* const* d_in, const int* in_sizes, int n_in,
                              void* d_out, int out_size, void* d_ws, size_t ws_size,
                              hipStream_t stream)
{
    const float* x      = (const float*)d_in[0];
    const int*   eidx   = (const int*)  d_in[1];
    const float* W1     = (const float*)d_in[2];
    const float* a_src1 = (const float*)d_in[3];
    const float* a_dst1 = (const float*)d_in[4];
    const float* b1     = (const float*)d_in[5];
    const float* W2     = (const float*)d_in[6];
    const float* a_src2 = (const float*)d_in[7];
    const float* a_dst2 = (const float*)d_in[8];
    const float* b2     = (const float*)d_in[9];

    int n = in_sizes[0] / 128;
    int E = in_sizes[1] / 2;
    const int* src = eidx;
    const int* dst = eidx + E;

    int NC = (E + CHUNK - 1) / CHUNK;   // 98 for E=1.6M
    int NB = (n + 255) / 256;           // 196 for n=50000 (<=256 required)

    char* ws = (char*)d_ws;
    size_t off = 0;
    auto alloc = [&](size_t bytes) { size_t o = off; off += (bytes + 255) & ~(size_t)255; return o; };

    unsigned* h1b   = (unsigned*)(ws + alloc((size_t)n * 64 * 4));   // 12.8 MB
    float2* as1     = (float2*)(ws + alloc((size_t)n * 8));
    float2* ad1     = (float2*)(ws + alloc((size_t)n * 8));
    float*  h2      = (float*) (ws + alloc((size_t)n * 4));
    int*    rowst   = (int*)   (ws + alloc((size_t)(n + 1) * 4));
    unsigned* keys  = (unsigned*)(ws + alloc(256));                  // [as0max, as1max]
    float*  wt      = (float*) (ws + alloc(512 * 4));                // w~[128][4]
    int*    osc     = (int*)   (ws + alloc((size_t)NB * NC * 4));    // 77 KB
    unsigned* pairs = (unsigned*)(ws + alloc((size_t)E * 4));        // 6.4 MB (packed)
    int*    csr_src = (int*)   (ws + alloc((size_t)E * 4));          // 6.4 MB
    (void)ws_size; (void)n_in; (void)out_size;

    hipMemsetAsync(keys, 0x00, 8, stream);   // max slots -> smallest key

    wtilde_kernel<<<2, 256, 0, stream>>>(W1, a_src1, a_dst1, wt);
    alpha_kernel<<<1024, 256, 0, stream>>>(x, wt, as1, ad1, keys, n);
    gemm_mfma_kernel<<<(n + 63) / 64, 256, 0, stream>>>(x, W1, h1b, n);

    chist_kernel<<<NC, 256, 0, stream>>>(dst, E, NB, NC, osc);
    oscan_kernel<<<1, 1024, 0, stream>>>(osc, NB * NC);
    cscatter_kernel<<<NC, 256, 0, stream>>>(src, dst, E, NB, NC, osc, pairs);
    fsort_kernel<<<NB, 256, 0, stream>>>(pairs, osc, E, n, NB, NC, rowst, csr_src);

    gather1_kernel<<<(n + 3) / 4, 256, 0, stream>>>(h1b, as1, ad1, rowst, csr_src, b1, W2,
                                                    keys, h2, n);
    gather2_kernel<<<(n + 255) / 256, 256, 0, stream>>>(h2, rowst, csr_src, a_src2, a_dst2, b2,
                                                        (float*)d_out, n);
}